// Round 2
// baseline (635.823 us; speedup 1.0000x reference)
//
#include <hip/hip_runtime.h>

#define N_NODES 8192
#define N_EDGES 131072
#define NGRAPH  64
#define DIM     32
#define HID     128
#define SKD     4096      // 128*32 flattened kd
#define SROW    34        // fallback-path pad

__device__ __forceinline__ float sigmoidf_(float x) { return 1.0f / (1.0f + expf(-x)); }

// ---------------- prep kernels ----------------
__global__ void init_nodes_kernel(const float* __restrict__ x,
                                  const float* __restrict__ w,
                                  const float* __restrict__ b,
                                  float* __restrict__ out) {
  int idx = blockIdx.x * 256 + threadIdx.x;
  if (idx >= N_NODES * DIM) return;
  int n = idx >> 5, d = idx & 31;
  out[idx] = fmaxf(fmaf(x[n], w[d], b[d]), 0.0f);
}

__global__ void hist_kernel(const int* __restrict__ dst, int* __restrict__ counts) {
  int e = blockIdx.x * 256 + threadIdx.x;
  if (e < N_EDGES) atomicAdd(&counts[dst[e]], 1);
}

__global__ void scan_kernel(const int* __restrict__ counts,
                            int* __restrict__ offsets,
                            float* __restrict__ deg_inv) {
  __shared__ int sm[1024];
  int t = threadIdx.x;
  int base = t * 8;
  int loc[8];
  int s = 0;
#pragma unroll
  for (int i = 0; i < 8; ++i) { loc[i] = s; s += counts[base + i]; }
  sm[t] = s;
  __syncthreads();
  for (int off = 1; off < 1024; off <<= 1) {
    int v = (t >= off) ? sm[t - off] : 0;
    __syncthreads();
    sm[t] += v;
    __syncthreads();
  }
  int excl = (t > 0) ? sm[t - 1] : 0;
#pragma unroll
  for (int i = 0; i < 8; ++i) {
    offsets[base + i] = excl + loc[i];
    int c = counts[base + i];
    deg_inv[base + i] = 1.0f / (float)(c > 0 ? c : 1);
  }
  if (t == 1023) offsets[N_NODES] = sm[1023];
}

__global__ void scatter_kernel(const int* __restrict__ ei,
                               const float* __restrict__ ea,
                               const int* __restrict__ offsets,
                               int* __restrict__ cursor,
                               int* __restrict__ csr_src,
                               float2* __restrict__ csr_ea) {
  int e = blockIdx.x * 256 + threadIdx.x;
  if (e >= N_EDGES) return;
  int d = ei[N_EDGES + e];
  int pos = atomicAdd(&cursor[d], 1);
  int slot = offsets[d] + pos;
  csr_src[slot] = ei[e];
  csr_ea[slot] = make_float2(ea[2 * e], ea[2 * e + 1]);
}

__global__ void gstart_kernel(const int* __restrict__ batch, int* __restrict__ gstart) {
  int n = blockIdx.x * 256 + threadIdx.x;
  if (n >= N_NODES) return;
  int b = batch[n];
  if (n == 0) {
    for (int g = 0; g <= b; ++g) gstart[g] = 0;
  } else {
    int bp = batch[n - 1];
    for (int g = bp + 1; g <= b; ++g) gstart[g] = n;
  }
  if (n == N_NODES - 1) {
    for (int g = b + 1; g <= NGRAPH; ++g) gstart[g] = N_NODES;
  }
}

// ================= NEW PATH =================
// Kernel A: per-node S[n,k,d] = sum_e hid[e,k]*out[src,d] held in registers
// (G=4 nodes, 64 acc VGPRs), written coalesced. Also O[n,d] = sum out[src,d].
__global__ __launch_bounds__(256) void build_s_kernel(
    const float* __restrict__ out_cur, const int* __restrict__ offsets,
    const int* __restrict__ csr_src, const float2* __restrict__ csr_ea,
    const float* __restrict__ w1, const float* __restrict__ b1,
    float* __restrict__ S, float* __restrict__ O) {
  constexpr int C = 16;
  __shared__ float hidb[C * HID];   // 8 KB
  __shared__ float osrcb[C * DIM];  // 2 KB
  __shared__ int offs[5];
  const int t = threadIdx.x;
  const int node0 = blockIdx.x * 4;
  if (t <= 4) offs[t] = offsets[node0 + t];
  const int k0 = (t >> 3) * 4, d0 = (t & 7) * 4;
  const int ec = t >> 4;   // edge slot (C=16)
  const int sub = t & 15;  // sub-slice
  float acc[4][4][4];
#pragma unroll
  for (int g = 0; g < 4; ++g)
#pragma unroll
    for (int i = 0; i < 4; ++i)
#pragma unroll
      for (int j = 0; j < 4; ++j) acc[g][i][j] = 0.0f;
  float oacc[4] = {0.0f, 0.0f, 0.0f, 0.0f};
  __syncthreads();
#pragma unroll
  for (int g = 0; g < 4; ++g) {
    const int base = offs[g], end = offs[g + 1];
    for (int c0 = base; c0 < end; c0 += C) {
      const int cnt = min(C, end - c0);
      __syncthreads();
      if (ec < cnt) {
        const int slot = c0 + ec;
        const float2 eav = csr_ea[slot];
        const int sidx = csr_src[slot];
#pragma unroll
        for (int i = 0; i < 8; ++i) {
          const int k = sub * 8 + i;
          hidb[ec * HID + k] =
              fmaxf(fmaf(eav.y, w1[HID + k], fmaf(eav.x, w1[k], b1[k])), 0.0f);
        }
        *(float2*)(osrcb + ec * DIM + sub * 2) =
            *(const float2*)(out_cur + sidx * DIM + sub * 2);
      }
      __syncthreads();
      for (int e = 0; e < cnt; ++e) {
        const float4 hv = *(const float4*)(hidb + e * HID + k0);
        const float4 ov = *(const float4*)(osrcb + e * DIM + d0);
        acc[g][0][0] = fmaf(hv.x, ov.x, acc[g][0][0]);
        acc[g][0][1] = fmaf(hv.x, ov.y, acc[g][0][1]);
        acc[g][0][2] = fmaf(hv.x, ov.z, acc[g][0][2]);
        acc[g][0][3] = fmaf(hv.x, ov.w, acc[g][0][3]);
        acc[g][1][0] = fmaf(hv.y, ov.x, acc[g][1][0]);
        acc[g][1][1] = fmaf(hv.y, ov.y, acc[g][1][1]);
        acc[g][1][2] = fmaf(hv.y, ov.z, acc[g][1][2]);
        acc[g][1][3] = fmaf(hv.y, ov.w, acc[g][1][3]);
        acc[g][2][0] = fmaf(hv.z, ov.x, acc[g][2][0]);
        acc[g][2][1] = fmaf(hv.z, ov.y, acc[g][2][1]);
        acc[g][2][2] = fmaf(hv.z, ov.z, acc[g][2][2]);
        acc[g][2][3] = fmaf(hv.z, ov.w, acc[g][2][3]);
        acc[g][3][0] = fmaf(hv.w, ov.x, acc[g][3][0]);
        acc[g][3][1] = fmaf(hv.w, ov.y, acc[g][3][1]);
        acc[g][3][2] = fmaf(hv.w, ov.z, acc[g][3][2]);
        acc[g][3][3] = fmaf(hv.w, ov.w, acc[g][3][3]);
        if (t < DIM) oacc[g] += osrcb[e * DIM + t];
      }
    }
  }
#pragma unroll
  for (int g = 0; g < 4; ++g) {
    const int node = node0 + g;
    float* Sp = S + node * SKD + k0 * DIM + d0;
#pragma unroll
    for (int i = 0; i < 4; ++i)
      *(float4*)(Sp + i * DIM) =
          make_float4(acc[g][i][0], acc[g][i][1], acc[g][i][2], acc[g][i][3]);
    if (t < DIM) O[node * DIM + t] = oacc[g];
  }
}

// Kernel B: partial[slice][n][o] = sum_{kd in slice} S[n][kd] * w2[kd*32+o]
// grid = 128 node-blocks x 4 kd-quarters; block = 256 th = 4 waves;
// wave w covers kd sub-slice; lanes = 8 node-groups x 8 o-quads; acc 8n x 4o.
#define SBPAD 68
__global__ __launch_bounds__(256) void contract_kernel(
    const float* __restrict__ S, const float* __restrict__ w2,
    float* __restrict__ partial) {
  __shared__ float sb[64 * SBPAD];  // 17.4 KB, layout [kd_local][node]
  const int t = threadIdx.x;
  const int nb = blockIdx.x >> 2;
  const int kqb = blockIdx.x & 3;
  const int node0 = nb * 64;
  const int kbase = kqb * 1024;
  const int w = t >> 6;
  const int lane = t & 63;
  const int ng = (lane >> 3) & 7;  // node group (8 nodes)
  const int og = lane & 7;         // o quad
  const int o0 = og * 4;
  float acc[8][4];
#pragma unroll
  for (int i = 0; i < 8; ++i)
#pragma unroll
    for (int j = 0; j < 4; ++j) acc[i][j] = 0.0f;

  const int ld_node = t >> 2;          // 0..63
  const int ld_kds = (t & 3) * 16;     // 0,16,32,48

  for (int c = 0; c < 16; ++c) {
    __syncthreads();
    // stage chunk [64 nodes][64 kd] -> sb[kd][node] (transposed)
    const float* gsrc = S + (size_t)(node0 + ld_node) * SKD + kbase + c * 64 + ld_kds;
#pragma unroll
    for (int i = 0; i < 4; ++i) {
      const float4 v = *(const float4*)(gsrc + i * 4);
      const int kl = ld_kds + i * 4;
      sb[(kl + 0) * SBPAD + ld_node] = v.x;
      sb[(kl + 1) * SBPAD + ld_node] = v.y;
      sb[(kl + 2) * SBPAD + ld_node] = v.z;
      sb[(kl + 3) * SBPAD + ld_node] = v.w;
    }
    __syncthreads();
    // wave w processes kd_local in [w*16, w*16+16)
#pragma unroll
    for (int k4 = 0; k4 < 4; ++k4) {
#pragma unroll
      for (int kk = 0; kk < 4; ++kk) {
        const int kdl = w * 16 + k4 * 4 + kk;
        const int kd = kbase + c * 64 + kdl;
        const float4 wv = *(const float4*)(w2 + (size_t)kd * 32 + o0);
        const float4 sa = *(const float4*)(sb + kdl * SBPAD + ng * 8);
        const float4 sc = *(const float4*)(sb + kdl * SBPAD + ng * 8 + 4);
        acc[0][0] = fmaf(sa.x, wv.x, acc[0][0]);
        acc[0][1] = fmaf(sa.x, wv.y, acc[0][1]);
        acc[0][2] = fmaf(sa.x, wv.z, acc[0][2]);
        acc[0][3] = fmaf(sa.x, wv.w, acc[0][3]);
        acc[1][0] = fmaf(sa.y, wv.x, acc[1][0]);
        acc[1][1] = fmaf(sa.y, wv.y, acc[1][1]);
        acc[1][2] = fmaf(sa.y, wv.z, acc[1][2]);
        acc[1][3] = fmaf(sa.y, wv.w, acc[1][3]);
        acc[2][0] = fmaf(sa.z, wv.x, acc[2][0]);
        acc[2][1] = fmaf(sa.z, wv.y, acc[2][1]);
        acc[2][2] = fmaf(sa.z, wv.z, acc[2][2]);
        acc[2][3] = fmaf(sa.z, wv.w, acc[2][3]);
        acc[3][0] = fmaf(sa.w, wv.x, acc[3][0]);
        acc[3][1] = fmaf(sa.w, wv.y, acc[3][1]);
        acc[3][2] = fmaf(sa.w, wv.z, acc[3][2]);
        acc[3][3] = fmaf(sa.w, wv.w, acc[3][3]);
        acc[4][0] = fmaf(sc.x, wv.x, acc[4][0]);
        acc[4][1] = fmaf(sc.x, wv.y, acc[4][1]);
        acc[4][2] = fmaf(sc.x, wv.z, acc[4][2]);
        acc[4][3] = fmaf(sc.x, wv.w, acc[4][3]);
        acc[5][0] = fmaf(sc.y, wv.x, acc[5][0]);
        acc[5][1] = fmaf(sc.y, wv.y, acc[5][1]);
        acc[5][2] = fmaf(sc.y, wv.z, acc[5][2]);
        acc[5][3] = fmaf(sc.y, wv.w, acc[5][3]);
        acc[6][0] = fmaf(sc.z, wv.x, acc[6][0]);
        acc[6][1] = fmaf(sc.z, wv.y, acc[6][1]);
        acc[6][2] = fmaf(sc.z, wv.z, acc[6][2]);
        acc[6][3] = fmaf(sc.z, wv.w, acc[6][3]);
        acc[7][0] = fmaf(sc.w, wv.x, acc[7][0]);
        acc[7][1] = fmaf(sc.w, wv.y, acc[7][1]);
        acc[7][2] = fmaf(sc.w, wv.z, acc[7][2]);
        acc[7][3] = fmaf(sc.w, wv.w, acc[7][3]);
      }
    }
  }
  // each wave writes its own partial slice (16 slices total)
  const int slice = kqb * 4 + w;
  float* pp = partial + ((size_t)slice * N_NODES + node0 + ng * 8) * DIM + o0;
#pragma unroll
  for (int i = 0; i < 8; ++i)
    *(float4*)(pp + i * DIM) = make_float4(acc[i][0], acc[i][1], acc[i][2], acc[i][3]);
}

// Kernel C: epilogue — sum 16 partials, + O*b2, /deg, + root, GRU
__global__ __launch_bounds__(256) void epilogue_kernel(
    const float* __restrict__ partial, const float* __restrict__ O,
    const float* __restrict__ out_cur, const float* __restrict__ b2,
    const float* __restrict__ deg_inv, const float* __restrict__ root_w,
    const float* __restrict__ conv_b, const float* __restrict__ gwih,
    const float* __restrict__ gwhh, const float* __restrict__ gbih,
    const float* __restrict__ gbhh, float* __restrict__ out_nxt) {
  __shared__ float hb[256], ob[256], mb[256], b2s[1024];
  const int t = threadIdx.x;
  const int node0 = blockIdx.x * 8;
  hb[t] = out_cur[node0 * DIM + t];
  ob[t] = O[node0 * DIM + t];
#pragma unroll
  for (int i = 0; i < 4; ++i) b2s[i * 256 + t] = b2[i * 256 + t];
  __syncthreads();
  const int g = t >> 5, o = t & 31;
  const int node = node0 + g;
  float agg = 0.0f;
#pragma unroll
  for (int s = 0; s < 16; ++s) agg += partial[(size_t)s * N_NODES * DIM + node * DIM + o];
#pragma unroll
  for (int d = 0; d < DIM; ++d) agg = fmaf(ob[g * DIM + d], b2s[d * DIM + o], agg);
  agg *= deg_inv[node];
  float rt = conv_b[o];
#pragma unroll
  for (int d = 0; d < DIM; ++d) rt = fmaf(hb[g * DIM + d], root_w[d * DIM + o], rt);
  mb[t] = fmaxf(agg + rt, 0.0f);
  __syncthreads();
  float gi[3], gh[3];
#pragma unroll
  for (int jj = 0; jj < 3; ++jj) {
    float si = gbih[jj * DIM + o], sh = gbhh[jj * DIM + o];
#pragma unroll
    for (int d = 0; d < DIM; ++d) {
      si = fmaf(mb[g * DIM + d], gwih[d * 3 * DIM + jj * DIM + o], si);
      sh = fmaf(hb[g * DIM + d], gwhh[d * 3 * DIM + jj * DIM + o], sh);
    }
    gi[jj] = si;
    gh[jj] = sh;
  }
  const float r = sigmoidf_(gi[0] + gh[0]);
  const float z = sigmoidf_(gi[1] + gh[1]);
  const float nn = tanhf(fmaf(r, gh[2], gi[2]));
  out_nxt[node * DIM + o] = (1.0f - z) * nn + z * hb[t];
}

// ================= FALLBACK (round-1 fused kernel, used if ws too small) ====
template <int G, int C>
__global__ __launch_bounds__(256) void mp_kernel(
    const float* __restrict__ out_cur, float* __restrict__ out_nxt,
    const int* __restrict__ offsets, const float* __restrict__ deg_inv,
    const int* __restrict__ csr_src, const float2* __restrict__ csr_ea,
    const float* __restrict__ w1, const float* __restrict__ b1,
    const float* __restrict__ w2, const float* __restrict__ b2,
    const float* __restrict__ root_w, const float* __restrict__ conv_b,
    const float* __restrict__ gwih, const float* __restrict__ gwhh,
    const float* __restrict__ gbih, const float* __restrict__ gbhh) {
  __shared__ float S[G * HID * SROW];
  __shared__ float hidb[C * HID];
  __shared__ float osrcb[C * DIM];
  __shared__ float Ob[G * DIM];
  __shared__ float aggb[G * DIM];
  __shared__ float mb[G * DIM];
  __shared__ float hb[G * DIM];
  __shared__ int offs[G + 1];
  __shared__ float dinvb[G];
  const int t = threadIdx.x;
  const int node0 = blockIdx.x * G;
  if (t <= G) offs[t] = offsets[min(node0 + t, N_NODES)];
  if (t < G) dinvb[t] = deg_inv[min(node0 + t, N_NODES - 1)];
  const int kg = t >> 3, dg = t & 7;
  const int k0 = kg * 4, d0 = dg * 4;
  const int ec = t / (256 / C);
  const int sub = t % (256 / C);
  __syncthreads();
  for (int g = 0; g < G; ++g) {
    float acc[4][4];
#pragma unroll
    for (int i = 0; i < 4; ++i)
#pragma unroll
      for (int j = 0; j < 4; ++j) acc[i][j] = 0.0f;
    float oacc = 0.0f;
    const int base = offs[g], end = offs[g + 1];
    for (int c0 = base; c0 < end; c0 += C) {
      const int cnt = min(C, end - c0);
      __syncthreads();
      if (ec < cnt) {
        const int slot = c0 + ec;
        const float2 eav = csr_ea[slot];
        const int sidx = csr_src[slot];
#pragma unroll
        for (int i = 0; i < HID / (256 / C); ++i) {
          const int k = sub * (HID / (256 / C)) + i;
          float v = fmaf(eav.y, w1[HID + k], fmaf(eav.x, w1[k], b1[k]));
          hidb[ec * HID + k] = fmaxf(v, 0.0f);
        }
        const float2 ovv = *(const float2*)(out_cur + sidx * DIM + sub * 2);
        *(float2*)(osrcb + ec * DIM + sub * 2) = ovv;
      }
      __syncthreads();
      for (int e = 0; e < cnt; ++e) {
        const float4 hv = *(const float4*)(hidb + e * HID + k0);
        const float4 ov = *(const float4*)(osrcb + e * DIM + d0);
        acc[0][0] = fmaf(hv.x, ov.x, acc[0][0]);
        acc[0][1] = fmaf(hv.x, ov.y, acc[0][1]);
        acc[0][2] = fmaf(hv.x, ov.z, acc[0][2]);
        acc[0][3] = fmaf(hv.x, ov.w, acc[0][3]);
        acc[1][0] = fmaf(hv.y, ov.x, acc[1][0]);
        acc[1][1] = fmaf(hv.y, ov.y, acc[1][1]);
        acc[1][2] = fmaf(hv.y, ov.z, acc[1][2]);
        acc[1][3] = fmaf(hv.y, ov.w, acc[1][3]);
        acc[2][0] = fmaf(hv.z, ov.x, acc[2][0]);
        acc[2][1] = fmaf(hv.z, ov.y, acc[2][1]);
        acc[2][2] = fmaf(hv.z, ov.z, acc[2][2]);
        acc[2][3] = fmaf(hv.z, ov.w, acc[2][3]);
        acc[3][0] = fmaf(hv.w, ov.x, acc[3][0]);
        acc[3][1] = fmaf(hv.w, ov.y, acc[3][1]);
        acc[3][2] = fmaf(hv.w, ov.z, acc[3][2]);
        acc[3][3] = fmaf(hv.w, ov.w, acc[3][3]);
        if (t < DIM) oacc += osrcb[e * DIM + t];
      }
    }
    float* Sg = S + g * HID * SROW;
#pragma unroll
    for (int i = 0; i < 4; ++i) {
      *(float2*)(Sg + (k0 + i) * SROW + d0) = make_float2(acc[i][0], acc[i][1]);
      *(float2*)(Sg + (k0 + i) * SROW + d0 + 2) = make_float2(acc[i][2], acc[i][3]);
    }
    if (t < DIM) Ob[g * DIM + t] = oacc;
  }
  __syncthreads();
  {
    const int ks = t >> 3, og = t & 7;
    const int o0 = og * 4;
    float a4[G][4];
#pragma unroll
    for (int g = 0; g < G; ++g)
#pragma unroll
      for (int j = 0; j < 4; ++j) a4[g][j] = 0.0f;
#pragma unroll
    for (int i = 0; i < 4; ++i) {
      const int k = ks * 4 + i;
      const float* w2k = w2 + k * (DIM * DIM);
#pragma unroll
      for (int dv = 0; dv < 8; ++dv) {
        const float4 wq0 = *(const float4*)(w2k + (dv * 4 + 0) * DIM + o0);
        const float4 wq1 = *(const float4*)(w2k + (dv * 4 + 1) * DIM + o0);
        const float4 wq2 = *(const float4*)(w2k + (dv * 4 + 2) * DIM + o0);
        const float4 wq3 = *(const float4*)(w2k + (dv * 4 + 3) * DIM + o0);
#pragma unroll
        for (int g = 0; g < G; ++g) {
          const float* Srow = S + g * HID * SROW + k * SROW + dv * 4;
          const float2 sa = *(const float2*)(Srow);
          const float2 sbv = *(const float2*)(Srow + 2);
          a4[g][0] = fmaf(sa.x, wq0.x, fmaf(sa.y, wq1.x, fmaf(sbv.x, wq2.x, fmaf(sbv.y, wq3.x, a4[g][0]))));
          a4[g][1] = fmaf(sa.x, wq0.y, fmaf(sa.y, wq1.y, fmaf(sbv.x, wq2.y, fmaf(sbv.y, wq3.y, a4[g][1]))));
          a4[g][2] = fmaf(sa.x, wq0.z, fmaf(sa.y, wq1.z, fmaf(sbv.x, wq2.z, fmaf(sbv.y, wq3.z, a4[g][2]))));
          a4[g][3] = fmaf(sa.x, wq0.w, fmaf(sa.y, wq1.w, fmaf(sbv.x, wq2.w, fmaf(sbv.y, wq3.w, a4[g][3]))));
        }
      }
    }
    __syncthreads();
#pragma unroll
    for (int g = 0; g < G; ++g)
#pragma unroll
      for (int j = 0; j < 4; ++j) S[(g * 4 + j) * 256 + t] = a4[g][j];
  }
  __syncthreads();
  if (t < G * DIM) {
    const int g = t >> 5, o = t & 31;
    const int og = o >> 2, j = o & 3;
    float sum = 0.0f;
    for (int ks = 0; ks < 32; ++ks) sum += S[(g * 4 + j) * 256 + ks * 8 + og];
    float obv = 0.0f;
#pragma unroll
    for (int d = 0; d < DIM; ++d) obv = fmaf(Ob[g * DIM + d], b2[d * DIM + o], obv);
    aggb[t] = (sum + obv) * dinvb[g];
  }
  if (t < G * DIM) {
    const int g = t >> 5, o = t & 31;
    const int node = node0 + g;
    hb[t] = (node < N_NODES) ? out_cur[node * DIM + o] : 0.0f;
  }
  __syncthreads();
  if (t < G * DIM) {
    const int g = t >> 5, o = t & 31;
    float rt = conv_b[o];
#pragma unroll
    for (int d = 0; d < DIM; ++d) rt = fmaf(hb[g * DIM + d], root_w[d * DIM + o], rt);
    mb[t] = fmaxf(aggb[t] + rt, 0.0f);
  }
  __syncthreads();
  if (t < G * DIM) {
    const int g = t >> 5, o = t & 31;
    const int node = node0 + g;
    if (node < N_NODES) {
      float gi[3], gh[3];
#pragma unroll
      for (int jj = 0; jj < 3; ++jj) {
        float si = gbih[jj * DIM + o], sh = gbhh[jj * DIM + o];
#pragma unroll
        for (int d = 0; d < DIM; ++d) {
          si = fmaf(mb[g * DIM + d], gwih[d * 3 * DIM + jj * DIM + o], si);
          sh = fmaf(hb[g * DIM + d], gwhh[d * 3 * DIM + jj * DIM + o], sh);
        }
        gi[jj] = si;
        gh[jj] = sh;
      }
      const float r = sigmoidf_(gi[0] + gh[0]);
      const float z = sigmoidf_(gi[1] + gh[1]);
      const float nn = tanhf(fmaf(r, gh[2], gi[2]));
      out_nxt[node * DIM + o] = (1.0f - z) * nn + z * hb[t];
    }
  }
}

// ---------------- Set2Set + head ----------------
__global__ __launch_bounds__(256) void s2s_kernel(
    const float* __restrict__ outf, const int* __restrict__ gstart,
    const float* __restrict__ wih, const float* __restrict__ whh,
    const float* __restrict__ bih, const float* __restrict__ bhh,
    const float* __restrict__ l1w, const float* __restrict__ l1b,
    const float* __restrict__ l2w, const float* __restrict__ l2b,
    float* __restrict__ y) {
  __shared__ float qh[DIM], qc[DIM], qstar[2 * DIM], gates[4 * DIM];
  __shared__ float wsum[4], wmax[4], wr[4][DIM];
  const int b = blockIdx.x, t = threadIdx.x;
  const int gs = gstart[b], ge = gstart[b + 1];
  const int w = t >> 6, lane = t & 63;
  if (t < DIM) { qh[t] = 0.0f; qc[t] = 0.0f; }
  if (t < 2 * DIM) qstar[t] = 0.0f;
  __syncthreads();
  for (int step = 0; step < 3; ++step) {
    if (t < 4 * DIM) {
      float gv = bih[t] + bhh[t];
      for (int i = 0; i < 2 * DIM; ++i) gv = fmaf(qstar[i], wih[i * 4 * DIM + t], gv);
      for (int i = 0; i < DIM; ++i) gv = fmaf(qh[i], whh[i * 4 * DIM + t], gv);
      gates[t] = gv;
    }
    __syncthreads();
    if (t < DIM) {
      const float ig = sigmoidf_(gates[t]);
      const float fg = sigmoidf_(gates[DIM + t]);
      const float gg = tanhf(gates[2 * DIM + t]);
      const float og = sigmoidf_(gates[3 * DIM + t]);
      const float c = fmaf(fg, qc[t], ig * gg);
      qc[t] = c;
      qh[t] = og * tanhf(c);
    }
    __syncthreads();
    float lmax = -INFINITY;
    for (int n = gs + t; n < ge; n += 256) {
      const float* orow = outf + n * DIM;
      float e = 0.0f;
#pragma unroll
      for (int d = 0; d < DIM; ++d) e = fmaf(orow[d], qh[d], e);
      lmax = fmaxf(lmax, e);
    }
#pragma unroll
    for (int off = 32; off > 0; off >>= 1) lmax = fmaxf(lmax, __shfl_xor(lmax, off));
    if (lane == 0) wmax[w] = lmax;
    __syncthreads();
    const float gmax = fmaxf(fmaxf(wmax[0], wmax[1]), fmaxf(wmax[2], wmax[3]));
    float rl[DIM];
#pragma unroll
    for (int d = 0; d < DIM; ++d) rl[d] = 0.0f;
    float lsum = 0.0f;
    for (int n = gs + t; n < ge; n += 256) {
      const float* orow = outf + n * DIM;
      float e = 0.0f;
#pragma unroll
      for (int d = 0; d < DIM; ++d) e = fmaf(orow[d], qh[d], e);
      const float a = expf(e - gmax);
      lsum += a;
#pragma unroll
      for (int d = 0; d < DIM; ++d) rl[d] = fmaf(a, orow[d], rl[d]);
    }
#pragma unroll
    for (int off = 32; off > 0; off >>= 1) {
      lsum += __shfl_xor(lsum, off);
#pragma unroll
      for (int d = 0; d < DIM; ++d) rl[d] += __shfl_xor(rl[d], off);
    }
    __syncthreads();
    if (lane == 0) {
      wsum[w] = lsum;
#pragma unroll
      for (int d = 0; d < DIM; ++d) wr[w][d] = rl[d];
    }
    __syncthreads();
    if (t < DIM) {
      const float stot = wsum[0] + wsum[1] + wsum[2] + wsum[3];
      const float rv = wr[0][t] + wr[1][t] + wr[2][t] + wr[3][t];
      qstar[t] = qh[t];
      qstar[DIM + t] = (stot > 0.0f) ? rv / stot : 0.0f;
    }
    __syncthreads();
  }
  if (t < DIM) {
    float u = l1b[t];
    for (int i = 0; i < 2 * DIM; ++i) u = fmaf(qstar[i], l1w[i * DIM + t], u);
    u = fmaxf(u, 0.0f);
    float v = u * l2w[t];
#pragma unroll
    for (int off = 16; off > 0; off >>= 1) v += __shfl_xor(v, off);
    if (t == 0) y[b] = v + l2b[0];
  }
}

extern "C" void kernel_launch(void* const* d_in, const int* in_sizes, int n_in,
                              void* d_out, int out_size, void* d_ws, size_t ws_size,
                              hipStream_t stream) {
  const float* x        = (const float*)d_in[0];
  const float* ea       = (const float*)d_in[1];
  const float* lin0_w   = (const float*)d_in[2];
  const float* lin0_b   = (const float*)d_in[3];
  const float* enn_w1   = (const float*)d_in[4];
  const float* enn_b1   = (const float*)d_in[5];
  const float* enn_w2   = (const float*)d_in[6];
  const float* enn_b2   = (const float*)d_in[7];
  const float* root_w   = (const float*)d_in[8];
  const float* conv_b   = (const float*)d_in[9];
  const float* gru_wih  = (const float*)d_in[10];
  const float* gru_whh  = (const float*)d_in[11];
  const float* gru_bih  = (const float*)d_in[12];
  const float* gru_bhh  = (const float*)d_in[13];
  const float* s2s_wih  = (const float*)d_in[14];
  const float* s2s_whh  = (const float*)d_in[15];
  const float* s2s_bih  = (const float*)d_in[16];
  const float* s2s_bhh  = (const float*)d_in[17];
  const float* lin1_w   = (const float*)d_in[18];
  const float* lin1_b   = (const float*)d_in[19];
  const float* lin2_w   = (const float*)d_in[20];
  const float* lin2_b   = (const float*)d_in[21];
  const int*   ei       = (const int*)d_in[22];
  const int*   batch    = (const int*)d_in[23];
  float* y = (float*)d_out;

  char* p = (char*)d_ws;
  auto alloc = [&](size_t bytes) -> void* {
    void* r = (void*)p;
    p += (bytes + 255) & ~(size_t)255;
    return r;
  };
  float*  out_a   = (float*)alloc(N_NODES * DIM * 4);
  float*  out_b   = (float*)alloc(N_NODES * DIM * 4);
  int*    counts  = (int*)alloc(N_NODES * 4);
  int*    offsets = (int*)alloc((N_NODES + 1) * 4);
  int*    cursor  = (int*)alloc(N_NODES * 4);
  int*    csr_src = (int*)alloc(N_EDGES * 4);
  float2* csr_ea  = (float2*)alloc(N_EDGES * 8);
  float*  deg_inv = (float*)alloc(N_NODES * 4);
  int*    gstart  = (int*)alloc((NGRAPH + 1) * 4);
  float*  Sbuf    = (float*)alloc((size_t)N_NODES * SKD * 4);   // 128 MB
  float*  Obuf    = (float*)alloc((size_t)N_NODES * DIM * 4);
  float*  partial = (float*)alloc((size_t)16 * N_NODES * DIM * 4);  // 16 MB
  const size_t need = (size_t)(p - (char*)d_ws);
  const bool big = (ws_size >= need);
  (void)n_in; (void)in_sizes; (void)out_size;

  hipMemsetAsync(counts, 0, N_NODES * 4, stream);
  hipMemsetAsync(cursor, 0, N_NODES * 4, stream);

  init_nodes_kernel<<<(N_NODES * DIM) / 256, 256, 0, stream>>>(x, lin0_w, lin0_b, out_a);
  hist_kernel<<<N_EDGES / 256, 256, 0, stream>>>(ei + N_EDGES, counts);
  scan_kernel<<<1, 1024, 0, stream>>>(counts, offsets, deg_inv);
  scatter_kernel<<<N_EDGES / 256, 256, 0, stream>>>(ei, ea, offsets, cursor, csr_src, csr_ea);
  gstart_kernel<<<N_NODES / 256, 256, 0, stream>>>(batch, gstart);

  if (big) {
    const float* cur = out_a;
    float* nxt = out_b;
    for (int layer = 0; layer < 3; ++layer) {
      build_s_kernel<<<N_NODES / 4, 256, 0, stream>>>(
          cur, offsets, csr_src, csr_ea, enn_w1, enn_b1, Sbuf, Obuf);
      contract_kernel<<<(N_NODES / 64) * 4, 256, 0, stream>>>(Sbuf, enn_w2, partial);
      epilogue_kernel<<<N_NODES / 8, 256, 0, stream>>>(
          partial, Obuf, cur, enn_b2, deg_inv, root_w, conv_b,
          gru_wih, gru_whh, gru_bih, gru_bhh, nxt);
      const float* tmp = cur; cur = nxt; nxt = (float*)tmp;
    }
    s2s_kernel<<<NGRAPH, 256, 0, stream>>>(cur, gstart, s2s_wih, s2s_whh, s2s_bih,
                                           s2s_bhh, lin1_w, lin1_b, lin2_w, lin2_b, y);
  } else {
    constexpr int G = 3, C = 16;
    const int mp_blocks = (N_NODES + G - 1) / G;
    mp_kernel<G, C><<<mp_blocks, 256, 0, stream>>>(
        out_a, out_b, offsets, deg_inv, csr_src, csr_ea, enn_w1, enn_b1, enn_w2,
        enn_b2, root_w, conv_b, gru_wih, gru_whh, gru_bih, gru_bhh);
    mp_kernel<G, C><<<mp_blocks, 256, 0, stream>>>(
        out_b, out_a, offsets, deg_inv, csr_src, csr_ea, enn_w1, enn_b1, enn_w2,
        enn_b2, root_w, conv_b, gru_wih, gru_whh, gru_bih, gru_bhh);
    mp_kernel<G, C><<<mp_blocks, 256, 0, stream>>>(
        out_a, out_b, offsets, deg_inv, csr_src, csr_ea, enn_w1, enn_b1, enn_w2,
        enn_b2, root_w, conv_b, gru_wih, gru_whh, gru_bih, gru_bhh);
    s2s_kernel<<<NGRAPH, 256, 0, stream>>>(out_b, gstart, s2s_wih, s2s_whh, s2s_bih,
                                           s2s_bhh, lin1_w, lin1_b, lin2_w, lin2_b, y);
  }
}

// Round 3
// 455.134 us; speedup vs baseline: 1.3970x; 1.3970x over previous
//
#include <hip/hip_runtime.h>

#define N_NODES 8192
#define N_EDGES 131072
#define NGRAPH  64
#define DIM     32
#define HID     128
#define KHALF   64         // k per half-block
#define G_NODES 3          // nodes per block
#define SROW    34         // padded d-stride for S tile (8B-aligned, bank-skewed)

__device__ __forceinline__ float sigmoidf_(float x) { return 1.0f / (1.0f + expf(-x)); }

// ---------------- prep ----------------
// blocks [0,1024): init node features; blocks [1024,1536): degree histogram
__global__ void prep1_kernel(const float* __restrict__ x, const float* __restrict__ w,
                             const float* __restrict__ b, float* __restrict__ out,
                             const int* __restrict__ dst, int* __restrict__ counts) {
  const int bb = blockIdx.x;
  if (bb < 1024) {
    int idx = bb * 256 + threadIdx.x;
    int n = idx >> 5, d = idx & 31;
    out[idx] = fmaxf(fmaf(x[n], w[d], b[d]), 0.0f);
  } else {
    int e = (bb - 1024) * 256 + threadIdx.x;
    atomicAdd(&counts[dst[e]], 1);
  }
}

__global__ void scan_kernel(const int* __restrict__ counts,
                            int* __restrict__ offsets,
                            float* __restrict__ deg_inv) {
  __shared__ int sm[1024];
  int t = threadIdx.x;
  int base = t * 8;
  int loc[8];
  int s = 0;
#pragma unroll
  for (int i = 0; i < 8; ++i) { loc[i] = s; s += counts[base + i]; }
  sm[t] = s;
  __syncthreads();
  for (int off = 1; off < 1024; off <<= 1) {
    int v = (t >= off) ? sm[t - off] : 0;
    __syncthreads();
    sm[t] += v;
    __syncthreads();
  }
  int excl = (t > 0) ? sm[t - 1] : 0;
#pragma unroll
  for (int i = 0; i < 8; ++i) {
    offsets[base + i] = excl + loc[i];
    int c = counts[base + i];
    deg_inv[base + i] = 1.0f / (float)(c > 0 ? c : 1);
  }
  if (t == 1023) offsets[N_NODES] = sm[1023];
}

// blocks [0,512): CSR scatter; blocks [512,544): graph-start table
__global__ void prep2_kernel(const int* __restrict__ ei, const float* __restrict__ ea,
                             const int* __restrict__ offsets, int* __restrict__ cursor,
                             int* __restrict__ csr_src, float2* __restrict__ csr_ea,
                             const int* __restrict__ batch, int* __restrict__ gstart) {
  const int bb = blockIdx.x;
  if (bb < 512) {
    int e = bb * 256 + threadIdx.x;
    int d = ei[N_EDGES + e];
    int pos = atomicAdd(&cursor[d], 1);
    int slot = offsets[d] + pos;
    csr_src[slot] = ei[e];
    csr_ea[slot] = make_float2(ea[2 * e], ea[2 * e + 1]);
  } else {
    int n = (bb - 512) * 256 + threadIdx.x;
    int b = batch[n];
    if (n == 0) {
      for (int g = 0; g <= b; ++g) gstart[g] = 0;
    } else {
      int bp = batch[n - 1];
      for (int g = bp + 1; g <= b; ++g) gstart[g] = n;
    }
    if (n == N_NODES - 1) {
      for (int g = b + 1; g <= NGRAPH; ++g) gstart[g] = N_NODES;
    }
  }
}

// ---------------- fused MP half-layer ----------------
// blockIdx = node-group*2 + khalf. Each block: G_NODES nodes, k in
// [khalf*64, khalf*64+64). Build S[g][k64][d32] in regs->LDS; contract with
// its w2 k-half (full 128B-line reads); cross-thread reduce via red (aliases
// S, dead after contract reads); write partial[khalf][n][o]. khalf==0 blocks
// also emit O[n][d] = sum_src out[src][d] for the b2-bias term.
__global__ __launch_bounds__(256, 4) void mp_half_kernel(
    const float* __restrict__ out_cur, const int* __restrict__ offsets,
    const int* __restrict__ csr_src, const float2* __restrict__ csr_ea,
    const float* __restrict__ w1, const float* __restrict__ b1,
    const float* __restrict__ w2, float* __restrict__ partial,
    float* __restrict__ O) {
  constexpr int C = 16;
  // smem carve: S (6528 f) | hidb (1024 f) | osrcb (512 f); red aliases S.
  __shared__ float smem[G_NODES * KHALF * SROW + C * KHALF + C * DIM];
  float* S = smem;
  float* hidb = smem + G_NODES * KHALF * SROW;
  float* osrcb = hidb + C * KHALF;
  float* red = smem;  // 12*256 = 3072 f <= 6528 f, reused after barrier
  __shared__ int offs[G_NODES + 1];

  const int t = threadIdx.x;
  const int bb = blockIdx.x;
  const int khalf = bb & 1;
  const int node0 = (bb >> 1) * G_NODES;

  if (t <= G_NODES) offs[t] = offsets[min(node0 + t, N_NODES)];

  // build map: thread = (kg 0..15)*4k x (dg 0..15)*2d
  const int kg = t >> 4, dg = t & 15;
  const int k0 = kg * 4, d0 = dg * 2;
  // staging map: edge slot ec, sub-slice sub
  const int ec = t >> 4, sub = t & 15;

  float acc[G_NODES][4][2];
#pragma unroll
  for (int g = 0; g < G_NODES; ++g)
#pragma unroll
    for (int i = 0; i < 4; ++i) { acc[g][i][0] = 0.0f; acc[g][i][1] = 0.0f; }
  float oacc[G_NODES] = {0.0f, 0.0f, 0.0f};
  __syncthreads();

#pragma unroll
  for (int g = 0; g < G_NODES; ++g) {
    const int base = offs[g], end = offs[g + 1];
    for (int c0 = base; c0 < end; c0 += C) {
      const int cnt = min(C, end - c0);
      __syncthreads();
      if (ec < cnt) {
        const int slot = c0 + ec;
        const float2 eav = csr_ea[slot];
        const int sidx = csr_src[slot];
#pragma unroll
        for (int i = 0; i < 4; ++i) {
          const int kl = sub * 4 + i;
          const int kgl = khalf * KHALF + kl;
          hidb[ec * KHALF + kl] =
              fmaxf(fmaf(eav.y, w1[HID + kgl], fmaf(eav.x, w1[kgl], b1[kgl])), 0.0f);
        }
        *(float2*)(osrcb + ec * DIM + sub * 2) =
            *(const float2*)(out_cur + sidx * DIM + sub * 2);
      }
      __syncthreads();
      for (int e = 0; e < cnt; ++e) {
        const float4 hv = *(const float4*)(hidb + e * KHALF + k0);
        const float2 ov = *(const float2*)(osrcb + e * DIM + d0);
        acc[g][0][0] = fmaf(hv.x, ov.x, acc[g][0][0]);
        acc[g][0][1] = fmaf(hv.x, ov.y, acc[g][0][1]);
        acc[g][1][0] = fmaf(hv.y, ov.x, acc[g][1][0]);
        acc[g][1][1] = fmaf(hv.y, ov.y, acc[g][1][1]);
        acc[g][2][0] = fmaf(hv.z, ov.x, acc[g][2][0]);
        acc[g][2][1] = fmaf(hv.z, ov.y, acc[g][2][1]);
        acc[g][3][0] = fmaf(hv.w, ov.x, acc[g][3][0]);
        acc[g][3][1] = fmaf(hv.w, ov.y, acc[g][3][1]);
        if (khalf == 0 && t < DIM) oacc[g] += osrcb[e * DIM + t];
      }
    }
  }
  // dump S tiles: S[g][kl][d] at g*64*SROW + kl*SROW + d  (float2, 8B-aligned)
#pragma unroll
  for (int g = 0; g < G_NODES; ++g) {
    float* Sg = S + g * KHALF * SROW;
#pragma unroll
    for (int i = 0; i < 4; ++i)
      *(float2*)(Sg + (k0 + i) * SROW + d0) = make_float2(acc[g][i][0], acc[g][i][1]);
  }
  if (khalf == 0 && t < DIM) {
#pragma unroll
    for (int g = 0; g < G_NODES; ++g) {
      const int node = node0 + g;
      if (node < N_NODES) O[node * DIM + t] = oacc[g];
    }
  }
  __syncthreads();

  // contract: thread = (ks 0..15, dvh 0..1, og 0..7)
  {
    const int ks = t >> 4;
    const int dvh = (t >> 3) & 1;
    const int og = t & 7;
    float a4[G_NODES][4];
#pragma unroll
    for (int g = 0; g < G_NODES; ++g)
#pragma unroll
      for (int r = 0; r < 4; ++r) a4[g][r] = 0.0f;
#pragma unroll
    for (int i = 0; i < 4; ++i) {
      const int kl = ks * 4 + i;
      const float* w2k = w2 + (size_t)(khalf * KHALF + kl) * (DIM * DIM);
#pragma unroll
      for (int dvi = 0; dvi < 4; ++dvi) {
        const int dv = dvh * 4 + dvi;
#pragma unroll
        for (int r = 0; r < 4; ++r) {
          const int d = dv * 4 + r;
          const float4 wv = *(const float4*)(w2k + d * DIM + og * 4);
#pragma unroll
          for (int g = 0; g < G_NODES; ++g) {
            const float sv = S[g * KHALF * SROW + kl * SROW + d];
            a4[g][0] = fmaf(sv, wv.x, a4[g][0]);
            a4[g][1] = fmaf(sv, wv.y, a4[g][1]);
            a4[g][2] = fmaf(sv, wv.z, a4[g][2]);
            a4[g][3] = fmaf(sv, wv.w, a4[g][3]);
          }
        }
      }
    }
    __syncthreads();  // all S reads done; red may now alias S
#pragma unroll
    for (int g = 0; g < G_NODES; ++g)
#pragma unroll
      for (int r = 0; r < 4; ++r) red[(g * 4 + r) * 256 + t] = a4[g][r];
  }
  __syncthreads();
  // reduce 32 (ks,dvh) contributions per (g,o) cell and write partial
  if (t < G_NODES * DIM) {
    const int g = t >> 5, o = t & 31;
    const int og = o >> 2, r = o & 3;
    const float* rp = red + (g * 4 + r) * 256 + og;
    float sum = 0.0f;
#pragma unroll
    for (int j = 0; j < 32; ++j) sum += rp[j * 8];
    const int node = node0 + g;
    if (node < N_NODES)
      partial[(size_t)khalf * N_NODES * DIM + node * DIM + o] = sum;
  }
}

// ---------------- epilogue: combine halves + bias + root + GRU ----------------
__global__ __launch_bounds__(256) void epilogue_kernel(
    const float* __restrict__ partial, const float* __restrict__ O,
    const float* __restrict__ out_cur, const float* __restrict__ b2,
    const float* __restrict__ deg_inv, const float* __restrict__ root_w,
    const float* __restrict__ conv_b, const float* __restrict__ gwih,
    const float* __restrict__ gwhh, const float* __restrict__ gbih,
    const float* __restrict__ gbhh, float* __restrict__ out_nxt) {
  __shared__ float hb[256], ob[256], mb[256], b2s[1024];
  const int t = threadIdx.x;
  const int node0 = blockIdx.x * 8;
  hb[t] = out_cur[node0 * DIM + t];
  ob[t] = O[node0 * DIM + t];
#pragma unroll
  for (int i = 0; i < 4; ++i) b2s[i * 256 + t] = b2[i * 256 + t];
  __syncthreads();
  const int g = t >> 5, o = t & 31;
  const int node = node0 + g;
  float agg = partial[node * DIM + o] +
              partial[(size_t)N_NODES * DIM + node * DIM + o];
#pragma unroll
  for (int d = 0; d < DIM; ++d) agg = fmaf(ob[g * DIM + d], b2s[d * DIM + o], agg);
  agg *= deg_inv[node];
  float rt = conv_b[o];
#pragma unroll
  for (int d = 0; d < DIM; ++d) rt = fmaf(hb[g * DIM + d], root_w[d * DIM + o], rt);
  mb[t] = fmaxf(agg + rt, 0.0f);
  __syncthreads();
  float gi[3], gh[3];
#pragma unroll
  for (int jj = 0; jj < 3; ++jj) {
    float si = gbih[jj * DIM + o], sh = gbhh[jj * DIM + o];
#pragma unroll
    for (int d = 0; d < DIM; ++d) {
      si = fmaf(mb[g * DIM + d], gwih[d * 3 * DIM + jj * DIM + o], si);
      sh = fmaf(hb[g * DIM + d], gwhh[d * 3 * DIM + jj * DIM + o], sh);
    }
    gi[jj] = si;
    gh[jj] = sh;
  }
  const float r = sigmoidf_(gi[0] + gh[0]);
  const float z = sigmoidf_(gi[1] + gh[1]);
  const float nn = tanhf(fmaf(r, gh[2], gi[2]));
  out_nxt[node * DIM + o] = (1.0f - z) * nn + z * hb[t];
}

// ---------------- Set2Set + head ----------------
__global__ __launch_bounds__(256) void s2s_kernel(
    const float* __restrict__ outf, const int* __restrict__ gstart,
    const float* __restrict__ wih, const float* __restrict__ whh,
    const float* __restrict__ bih, const float* __restrict__ bhh,
    const float* __restrict__ l1w, const float* __restrict__ l1b,
    const float* __restrict__ l2w, const float* __restrict__ l2b,
    float* __restrict__ y) {
  __shared__ float qh[DIM], qc[DIM], qstar[2 * DIM], gates[4 * DIM];
  __shared__ float wsum[4], wmax[4], wr[4][DIM];
  const int b = blockIdx.x, t = threadIdx.x;
  const int gs = gstart[b], ge = gstart[b + 1];
  const int w = t >> 6, lane = t & 63;
  if (t < DIM) { qh[t] = 0.0f; qc[t] = 0.0f; }
  if (t < 2 * DIM) qstar[t] = 0.0f;
  __syncthreads();
  for (int step = 0; step < 3; ++step) {
    if (t < 4 * DIM) {
      float gv = bih[t] + bhh[t];
      for (int i = 0; i < 2 * DIM; ++i) gv = fmaf(qstar[i], wih[i * 4 * DIM + t], gv);
      for (int i = 0; i < DIM; ++i) gv = fmaf(qh[i], whh[i * 4 * DIM + t], gv);
      gates[t] = gv;
    }
    __syncthreads();
    if (t < DIM) {
      const float ig = sigmoidf_(gates[t]);
      const float fg = sigmoidf_(gates[DIM + t]);
      const float gg = tanhf(gates[2 * DIM + t]);
      const float og = sigmoidf_(gates[3 * DIM + t]);
      const float c = fmaf(fg, qc[t], ig * gg);
      qc[t] = c;
      qh[t] = og * tanhf(c);
    }
    __syncthreads();
    float lmax = -INFINITY;
    for (int n = gs + t; n < ge; n += 256) {
      const float* orow = outf + n * DIM;
      float e = 0.0f;
#pragma unroll
      for (int d = 0; d < DIM; ++d) e = fmaf(orow[d], qh[d], e);
      lmax = fmaxf(lmax, e);
    }
#pragma unroll
    for (int off = 32; off > 0; off >>= 1) lmax = fmaxf(lmax, __shfl_xor(lmax, off));
    if (lane == 0) wmax[w] = lmax;
    __syncthreads();
    const float gmax = fmaxf(fmaxf(wmax[0], wmax[1]), fmaxf(wmax[2], wmax[3]));
    float rl[DIM];
#pragma unroll
    for (int d = 0; d < DIM; ++d) rl[d] = 0.0f;
    float lsum = 0.0f;
    for (int n = gs + t; n < ge; n += 256) {
      const float* orow = outf + n * DIM;
      float e = 0.0f;
#pragma unroll
      for (int d = 0; d < DIM; ++d) e = fmaf(orow[d], qh[d], e);
      const float a = expf(e - gmax);
      lsum += a;
#pragma unroll
      for (int d = 0; d < DIM; ++d) rl[d] = fmaf(a, orow[d], rl[d]);
    }
#pragma unroll
    for (int off = 32; off > 0; off >>= 1) {
      lsum += __shfl_xor(lsum, off);
#pragma unroll
      for (int d = 0; d < DIM; ++d) rl[d] += __shfl_xor(rl[d], off);
    }
    __syncthreads();
    if (lane == 0) {
      wsum[w] = lsum;
#pragma unroll
      for (int d = 0; d < DIM; ++d) wr[w][d] = rl[d];
    }
    __syncthreads();
    if (t < DIM) {
      const float stot = wsum[0] + wsum[1] + wsum[2] + wsum[3];
      const float rv = wr[0][t] + wr[1][t] + wr[2][t] + wr[3][t];
      qstar[t] = qh[t];
      qstar[DIM + t] = (stot > 0.0f) ? rv / stot : 0.0f;
    }
    __syncthreads();
  }
  if (t < DIM) {
    float u = l1b[t];
    for (int i = 0; i < 2 * DIM; ++i) u = fmaf(qstar[i], l1w[i * DIM + t], u);
    u = fmaxf(u, 0.0f);
    float v = u * l2w[t];
#pragma unroll
    for (int off = 16; off > 0; off >>= 1) v += __shfl_xor(v, off);
    if (t == 0) y[b] = v + l2b[0];
  }
}

extern "C" void kernel_launch(void* const* d_in, const int* in_sizes, int n_in,
                              void* d_out, int out_size, void* d_ws, size_t ws_size,
                              hipStream_t stream) {
  const float* x        = (const float*)d_in[0];
  const float* ea       = (const float*)d_in[1];
  const float* lin0_w   = (const float*)d_in[2];
  const float* lin0_b   = (const float*)d_in[3];
  const float* enn_w1   = (const float*)d_in[4];
  const float* enn_b1   = (const float*)d_in[5];
  const float* enn_w2   = (const float*)d_in[6];
  const float* enn_b2   = (const float*)d_in[7];
  const float* root_w   = (const float*)d_in[8];
  const float* conv_b   = (const float*)d_in[9];
  const float* gru_wih  = (const float*)d_in[10];
  const float* gru_whh  = (const float*)d_in[11];
  const float* gru_bih  = (const float*)d_in[12];
  const float* gru_bhh  = (const float*)d_in[13];
  const float* s2s_wih  = (const float*)d_in[14];
  const float* s2s_whh  = (const float*)d_in[15];
  const float* s2s_bih  = (const float*)d_in[16];
  const float* s2s_bhh  = (const float*)d_in[17];
  const float* lin1_w   = (const float*)d_in[18];
  const float* lin1_b   = (const float*)d_in[19];
  const float* lin2_w   = (const float*)d_in[20];
  const float* lin2_b   = (const float*)d_in[21];
  const int*   ei       = (const int*)d_in[22];
  const int*   batch    = (const int*)d_in[23];
  float* y = (float*)d_out;

  char* p = (char*)d_ws;
  auto alloc = [&](size_t bytes) -> void* {
    void* r = (void*)p;
    p += (bytes + 255) & ~(size_t)255;
    return r;
  };
  float*  out_a   = (float*)alloc(N_NODES * DIM * 4);
  float*  out_b   = (float*)alloc(N_NODES * DIM * 4);
  int*    counts  = (int*)alloc(N_NODES * 4);
  int*    offsets = (int*)alloc((N_NODES + 1) * 4);
  int*    cursor  = (int*)alloc(N_NODES * 4);
  int*    csr_src = (int*)alloc(N_EDGES * 4);
  float2* csr_ea  = (float2*)alloc(N_EDGES * 8);
  float*  deg_inv = (float*)alloc(N_NODES * 4);
  int*    gstart  = (int*)alloc((NGRAPH + 1) * 4);
  float*  Obuf    = (float*)alloc((size_t)N_NODES * DIM * 4);
  float*  partial = (float*)alloc((size_t)2 * N_NODES * DIM * 4);  // 2 MB
  (void)ws_size; (void)n_in; (void)in_sizes; (void)out_size;

  hipMemsetAsync(counts, 0, N_NODES * 4, stream);
  hipMemsetAsync(cursor, 0, N_NODES * 4, stream);

  prep1_kernel<<<1024 + 512, 256, 0, stream>>>(x, lin0_w, lin0_b, out_a,
                                               ei + N_EDGES, counts);
  scan_kernel<<<1, 1024, 0, stream>>>(counts, offsets, deg_inv);
  prep2_kernel<<<512 + 32, 256, 0, stream>>>(ei, ea, offsets, cursor, csr_src,
                                             csr_ea, batch, gstart);

  const int ngroups = (N_NODES + G_NODES - 1) / G_NODES;  // 2731
  const float* cur = out_a;
  float* nxt = out_b;
  for (int layer = 0; layer < 3; ++layer) {
    mp_half_kernel<<<ngroups * 2, 256, 0, stream>>>(
        cur, offsets, csr_src, csr_ea, enn_w1, enn_b1, enn_w2, partial, Obuf);
    epilogue_kernel<<<N_NODES / 8, 256, 0, stream>>>(
        partial, Obuf, cur, enn_b2, deg_inv, root_w, conv_b,
        gru_wih, gru_whh, gru_bih, gru_bhh, nxt);
    const float* tmp = cur; cur = nxt; nxt = (float*)tmp;
  }

  s2s_kernel<<<NGRAPH, 256, 0, stream>>>(cur, gstart, s2s_wih, s2s_whh, s2s_bih,
                                         s2s_bhh, lin1_w, lin1_b, lin2_w, lin2_b, y);
}

// Round 4
// 424.172 us; speedup vs baseline: 1.4990x; 1.0730x over previous
//
#include <hip/hip_runtime.h>

#define N_NODES 8192
#define N_EDGES 131072
#define NGRAPH  64
#define DIM     32
#define HID     128
#define KHALF   64         // k per half-block
#define G_NODES 3          // nodes per block
#define SROW    36         // S d-stride: 16B-aligned; +swizzle for bank spread

__device__ __forceinline__ float sigmoidf_(float x) { return 1.0f / (1.0f + expf(-x)); }

// ---------------- prep ----------------
// blocks [0,1024): init node features; blocks [1024,1536): degree histogram
__global__ void prep1_kernel(const float* __restrict__ x, const float* __restrict__ w,
                             const float* __restrict__ b, float* __restrict__ out,
                             const int* __restrict__ dst, int* __restrict__ counts) {
  const int bb = blockIdx.x;
  if (bb < 1024) {
    int idx = bb * 256 + threadIdx.x;
    int n = idx >> 5, d = idx & 31;
    out[idx] = fmaxf(fmaf(x[n], w[d], b[d]), 0.0f);
  } else {
    int e = (bb - 1024) * 256 + threadIdx.x;
    atomicAdd(&counts[dst[e]], 1);
  }
}

__global__ void scan_kernel(const int* __restrict__ counts,
                            int* __restrict__ offsets,
                            float* __restrict__ deg_inv) {
  __shared__ int sm[1024];
  int t = threadIdx.x;
  int base = t * 8;
  int loc[8];
  int s = 0;
#pragma unroll
  for (int i = 0; i < 8; ++i) { loc[i] = s; s += counts[base + i]; }
  sm[t] = s;
  __syncthreads();
  for (int off = 1; off < 1024; off <<= 1) {
    int v = (t >= off) ? sm[t - off] : 0;
    __syncthreads();
    sm[t] += v;
    __syncthreads();
  }
  int excl = (t > 0) ? sm[t - 1] : 0;
#pragma unroll
  for (int i = 0; i < 8; ++i) {
    offsets[base + i] = excl + loc[i];
    int c = counts[base + i];
    deg_inv[base + i] = 1.0f / (float)(c > 0 ? c : 1);
  }
  if (t == 1023) offsets[N_NODES] = sm[1023];
}

// blocks [0,512): CSR scatter; blocks [512,544): graph-start table
__global__ void prep2_kernel(const int* __restrict__ ei, const float* __restrict__ ea,
                             const int* __restrict__ offsets, int* __restrict__ cursor,
                             int* __restrict__ csr_src, float2* __restrict__ csr_ea,
                             const int* __restrict__ batch, int* __restrict__ gstart) {
  const int bb = blockIdx.x;
  if (bb < 512) {
    int e = bb * 256 + threadIdx.x;
    int d = ei[N_EDGES + e];
    int pos = atomicAdd(&cursor[d], 1);
    int slot = offsets[d] + pos;
    csr_src[slot] = ei[e];
    csr_ea[slot] = make_float2(ea[2 * e], ea[2 * e + 1]);
  } else {
    int n = (bb - 512) * 256 + threadIdx.x;
    int b = batch[n];
    if (n == 0) {
      for (int g = 0; g <= b; ++g) gstart[g] = 0;
    } else {
      int bp = batch[n - 1];
      for (int g = bp + 1; g <= b; ++g) gstart[g] = n;
    }
    if (n == N_NODES - 1) {
      for (int g = b + 1; g <= NGRAPH; ++g) gstart[g] = N_NODES;
    }
  }
}

// ---------------- fused MP half-layer ----------------
// blockIdx = node-group*2 + khalf. S[g][kl][d] swizzled: addr = kl*SROW +
// ((d + (kl>>2 & 3)*8) & 31). Staging buffers + reduction scratch alias the
// S region (S only written after staging is dead; red only after contract
// reads complete). LDS = 27.7 KB -> 5 blocks/CU.
__global__ __launch_bounds__(256, 5) void mp_half_kernel(
    const float* __restrict__ out_cur, const int* __restrict__ offsets,
    const int* __restrict__ csr_src, const float2* __restrict__ csr_ea,
    const float* __restrict__ w1, const float* __restrict__ b1,
    const float* __restrict__ w2, float* __restrict__ partial,
    float* __restrict__ O) {
  constexpr int C = 32;
  __shared__ float smem[G_NODES * KHALF * SROW];  // 6912 floats = 27648 B
  float* S = smem;
  float* hidb = smem;                // C*KHALF = 2048 floats (aliases S)
  float* osrcb = smem + C * KHALF;   // C*DIM = 1024 floats
  float* red = smem;                 // 12*257 = 3084 floats (aliases S)
  __shared__ int offs[G_NODES + 1];

  const int t = threadIdx.x;
  const int bb = blockIdx.x;
  const int khalf = bb & 1;
  const int node0 = (bb >> 1) * G_NODES;

  if (t <= G_NODES) offs[t] = offsets[min(node0 + t, N_NODES)];

  // build map: thread = (kg 0..15) x (dg 0..15); owns k0..k0+3, d0..d0+1
  const int kg = t >> 4, dg = t & 15;
  const int k0 = kg * 4, d0 = dg * 2;
  // staging map: edge slot ec (0..31), sub-slice sub (0..7)
  const int ec = t >> 3, sub = t & 7;

  // hoist w1/b1 (loop-invariant per thread)
  float w1x[8], w1y[8], b1v[8];
#pragma unroll
  for (int i = 0; i < 8; ++i) {
    const int kgl = khalf * KHALF + sub * 8 + i;
    w1x[i] = w1[kgl];
    w1y[i] = w1[HID + kgl];
    b1v[i] = b1[kgl];
  }

  float acc[G_NODES][4][2];
#pragma unroll
  for (int g = 0; g < G_NODES; ++g)
#pragma unroll
    for (int i = 0; i < 4; ++i) { acc[g][i][0] = 0.0f; acc[g][i][1] = 0.0f; }
  float oacc[G_NODES] = {0.0f, 0.0f, 0.0f};
  __syncthreads();

#pragma unroll
  for (int g = 0; g < G_NODES; ++g) {
    const int base = offs[g], end = offs[g + 1];
    for (int c0 = base; c0 < end; c0 += C) {
      const int cnt = min(C, end - c0);
      __syncthreads();  // previous chunk's readers done
      if (ec < cnt) {
        const int slot = c0 + ec;
        const float2 eav = csr_ea[slot];
        const int sidx = csr_src[slot];
        float hv[8];
#pragma unroll
        for (int i = 0; i < 8; ++i)
          hv[i] = fmaxf(fmaf(eav.y, w1y[i], fmaf(eav.x, w1x[i], b1v[i])), 0.0f);
        *(float4*)(hidb + ec * KHALF + sub * 8) =
            make_float4(hv[0], hv[1], hv[2], hv[3]);
        *(float4*)(hidb + ec * KHALF + sub * 8 + 4) =
            make_float4(hv[4], hv[5], hv[6], hv[7]);
        *(float4*)(osrcb + ec * DIM + sub * 4) =
            *(const float4*)(out_cur + sidx * DIM + sub * 4);
      }
      __syncthreads();
      for (int e = 0; e < cnt; ++e) {
        const float4 hvv = *(const float4*)(hidb + e * KHALF + k0);
        const float2 ov = *(const float2*)(osrcb + e * DIM + d0);
        acc[g][0][0] = fmaf(hvv.x, ov.x, acc[g][0][0]);
        acc[g][0][1] = fmaf(hvv.x, ov.y, acc[g][0][1]);
        acc[g][1][0] = fmaf(hvv.y, ov.x, acc[g][1][0]);
        acc[g][1][1] = fmaf(hvv.y, ov.y, acc[g][1][1]);
        acc[g][2][0] = fmaf(hvv.z, ov.x, acc[g][2][0]);
        acc[g][2][1] = fmaf(hvv.z, ov.y, acc[g][2][1]);
        acc[g][3][0] = fmaf(hvv.w, ov.x, acc[g][3][0]);
        acc[g][3][1] = fmaf(hvv.w, ov.y, acc[g][3][1]);
        if (khalf == 0 && t < DIM) oacc[g] += osrcb[e * DIM + t];
      }
    }
  }
  __syncthreads();  // staging dead everywhere; safe to overwrite with S

  // dump S tiles (swizzled): row kl, cols (d0 + (kg&3)*8) & 31
  {
    const int shift = (kg & 3) * 8;
    const int dd = (d0 + shift) & 31;
#pragma unroll
    for (int g = 0; g < G_NODES; ++g) {
      float* Sg = S + g * KHALF * SROW;
#pragma unroll
      for (int i = 0; i < 4; ++i)
        *(float2*)(Sg + (k0 + i) * SROW + dd) = make_float2(acc[g][i][0], acc[g][i][1]);
    }
  }
  if (khalf == 0 && t < DIM) {
#pragma unroll
    for (int g = 0; g < G_NODES; ++g) {
      const int node = node0 + g;
      if (node < N_NODES) O[node * DIM + t] = oacc[g];
    }
  }
  __syncthreads();

  // contract: thread = (ks 0..15, dvh 0..1, og 0..7)
  {
    const int ks = t >> 4;
    const int dvh = (t >> 3) & 1;
    const int og = t & 7;
    const int shift = (ks & 3) * 8;
    float a4[G_NODES][4];
#pragma unroll
    for (int g = 0; g < G_NODES; ++g)
#pragma unroll
      for (int r = 0; r < 4; ++r) a4[g][r] = 0.0f;
#pragma unroll
    for (int i = 0; i < 4; ++i) {
      const int kl = ks * 4 + i;
      const float* w2k = w2 + (size_t)(khalf * KHALF + kl) * (DIM * DIM);
#pragma unroll
      for (int q = 0; q < 4; ++q) {
        const int dbase = dvh * 16 + q * 4;
        const int dq = (dbase + shift) & 31;
        const float4 sv0 = *(const float4*)(S + 0 * KHALF * SROW + kl * SROW + dq);
        const float4 sv1 = *(const float4*)(S + 1 * KHALF * SROW + kl * SROW + dq);
        const float4 sv2 = *(const float4*)(S + 2 * KHALF * SROW + kl * SROW + dq);
        const float* s0 = (const float*)&sv0;
        const float* s1 = (const float*)&sv1;
        const float* s2 = (const float*)&sv2;
#pragma unroll
        for (int r = 0; r < 4; ++r) {
          const float4 wv = *(const float4*)(w2k + (dbase + r) * DIM + og * 4);
          a4[0][0] = fmaf(s0[r], wv.x, a4[0][0]);
          a4[0][1] = fmaf(s0[r], wv.y, a4[0][1]);
          a4[0][2] = fmaf(s0[r], wv.z, a4[0][2]);
          a4[0][3] = fmaf(s0[r], wv.w, a4[0][3]);
          a4[1][0] = fmaf(s1[r], wv.x, a4[1][0]);
          a4[1][1] = fmaf(s1[r], wv.y, a4[1][1]);
          a4[1][2] = fmaf(s1[r], wv.z, a4[1][2]);
          a4[1][3] = fmaf(s1[r], wv.w, a4[1][3]);
          a4[2][0] = fmaf(s2[r], wv.x, a4[2][0]);
          a4[2][1] = fmaf(s2[r], wv.y, a4[2][1]);
          a4[2][2] = fmaf(s2[r], wv.z, a4[2][2]);
          a4[2][3] = fmaf(s2[r], wv.w, a4[2][3]);
        }
      }
    }
    __syncthreads();  // all S reads done; red may alias S
#pragma unroll
    for (int g = 0; g < G_NODES; ++g)
#pragma unroll
      for (int r = 0; r < 4; ++r) red[(g * 4 + r) * 257 + t] = a4[g][r];
  }
  __syncthreads();
  // reduce 32 (ks,dvh) contributions per (g,o) cell and write partial
  if (t < G_NODES * DIM) {
    const int g = t >> 5, o = t & 31;
    const int og = o >> 2, r = o & 3;
    const float* rp = red + (g * 4 + r) * 257 + og;
    float sum = 0.0f;
#pragma unroll
    for (int j = 0; j < 32; ++j) sum += rp[j * 8];
    const int node = node0 + g;
    if (node < N_NODES)
      partial[(size_t)khalf * N_NODES * DIM + node * DIM + o] = sum;
  }
}

// ---------------- epilogue: combine halves + bias + root + GRU ----------------
__global__ __launch_bounds__(256) void epilogue_kernel(
    const float* __restrict__ partial, const float* __restrict__ O,
    const float* __restrict__ out_cur, const float* __restrict__ b2,
    const float* __restrict__ deg_inv, const float* __restrict__ root_w,
    const float* __restrict__ conv_b, const float* __restrict__ gwih,
    const float* __restrict__ gwhh, const float* __restrict__ gbih,
    const float* __restrict__ gbhh, float* __restrict__ out_nxt) {
  __shared__ float hb[256], ob[256], mb[256], b2s[1024];
  const int t = threadIdx.x;
  const int node0 = blockIdx.x * 8;
  hb[t] = out_cur[node0 * DIM + t];
  ob[t] = O[node0 * DIM + t];
#pragma unroll
  for (int i = 0; i < 4; ++i) b2s[i * 256 + t] = b2[i * 256 + t];
  __syncthreads();
  const int g = t >> 5, o = t & 31;
  const int node = node0 + g;
  float agg = partial[node * DIM + o] +
              partial[(size_t)N_NODES * DIM + node * DIM + o];
#pragma unroll
  for (int d = 0; d < DIM; ++d) agg = fmaf(ob[g * DIM + d], b2s[d * DIM + o], agg);
  agg *= deg_inv[node];
  float rt = conv_b[o];
#pragma unroll
  for (int d = 0; d < DIM; ++d) rt = fmaf(hb[g * DIM + d], root_w[d * DIM + o], rt);
  mb[t] = fmaxf(agg + rt, 0.0f);
  __syncthreads();
  float gi[3], gh[3];
#pragma unroll
  for (int jj = 0; jj < 3; ++jj) {
    float si = gbih[jj * DIM + o], sh = gbhh[jj * DIM + o];
#pragma unroll
    for (int d = 0; d < DIM; ++d) {
      si = fmaf(mb[g * DIM + d], gwih[d * 3 * DIM + jj * DIM + o], si);
      sh = fmaf(hb[g * DIM + d], gwhh[d * 3 * DIM + jj * DIM + o], sh);
    }
    gi[jj] = si;
    gh[jj] = sh;
  }
  const float r = sigmoidf_(gi[0] + gh[0]);
  const float z = sigmoidf_(gi[1] + gh[1]);
  const float nn = tanhf(fmaf(r, gh[2], gi[2]));
  out_nxt[node * DIM + o] = (1.0f - z) * nn + z * hb[t];
}

// ---------------- Set2Set + head ----------------
__global__ __launch_bounds__(256) void s2s_kernel(
    const float* __restrict__ outf, const int* __restrict__ gstart,
    const float* __restrict__ wih, const float* __restrict__ whh,
    const float* __restrict__ bih, const float* __restrict__ bhh,
    const float* __restrict__ l1w, const float* __restrict__ l1b,
    const float* __restrict__ l2w, const float* __restrict__ l2b,
    float* __restrict__ y) {
  __shared__ float qh[DIM], qc[DIM], qstar[2 * DIM], gates[4 * DIM];
  __shared__ float wsum[4], wmax[4], wr[4][DIM];
  const int b = blockIdx.x, t = threadIdx.x;
  const int gs = gstart[b], ge = gstart[b + 1];
  const int w = t >> 6, lane = t & 63;
  if (t < DIM) { qh[t] = 0.0f; qc[t] = 0.0f; }
  if (t < 2 * DIM) qstar[t] = 0.0f;
  __syncthreads();
  for (int step = 0; step < 3; ++step) {
    if (t < 4 * DIM) {
      float gv = bih[t] + bhh[t];
      for (int i = 0; i < 2 * DIM; ++i) gv = fmaf(qstar[i], wih[i * 4 * DIM + t], gv);
      for (int i = 0; i < DIM; ++i) gv = fmaf(qh[i], whh[i * 4 * DIM + t], gv);
      gates[t] = gv;
    }
    __syncthreads();
    if (t < DIM) {
      const float ig = sigmoidf_(gates[t]);
      const float fg = sigmoidf_(gates[DIM + t]);
      const float gg = tanhf(gates[2 * DIM + t]);
      const float og = sigmoidf_(gates[3 * DIM + t]);
      const float c = fmaf(fg, qc[t], ig * gg);
      qc[t] = c;
      qh[t] = og * tanhf(c);
    }
    __syncthreads();
    float lmax = -INFINITY;
    for (int n = gs + t; n < ge; n += 256) {
      const float* orow = outf + n * DIM;
      float e = 0.0f;
#pragma unroll
      for (int d = 0; d < DIM; ++d) e = fmaf(orow[d], qh[d], e);
      lmax = fmaxf(lmax, e);
    }
#pragma unroll
    for (int off = 32; off > 0; off >>= 1) lmax = fmaxf(lmax, __shfl_xor(lmax, off));
    if (lane == 0) wmax[w] = lmax;
    __syncthreads();
    const float gmax = fmaxf(fmaxf(wmax[0], wmax[1]), fmaxf(wmax[2], wmax[3]));
    float rl[DIM];
#pragma unroll
    for (int d = 0; d < DIM; ++d) rl[d] = 0.0f;
    float lsum = 0.0f;
    for (int n = gs + t; n < ge; n += 256) {
      const float* orow = outf + n * DIM;
      float e = 0.0f;
#pragma unroll
      for (int d = 0; d < DIM; ++d) e = fmaf(orow[d], qh[d], e);
      const float a = expf(e - gmax);
      lsum += a;
#pragma unroll
      for (int d = 0; d < DIM; ++d) rl[d] = fmaf(a, orow[d], rl[d]);
    }
#pragma unroll
    for (int off = 32; off > 0; off >>= 1) {
      lsum += __shfl_xor(lsum, off);
#pragma unroll
      for (int d = 0; d < DIM; ++d) rl[d] += __shfl_xor(rl[d], off);
    }
    __syncthreads();
    if (lane == 0) {
      wsum[w] = lsum;
#pragma unroll
      for (int d = 0; d < DIM; ++d) wr[w][d] = rl[d];
    }
    __syncthreads();
    if (t < DIM) {
      const float stot = wsum[0] + wsum[1] + wsum[2] + wsum[3];
      const float rv = wr[0][t] + wr[1][t] + wr[2][t] + wr[3][t];
      qstar[t] = qh[t];
      qstar[DIM + t] = (stot > 0.0f) ? rv / stot : 0.0f;
    }
    __syncthreads();
  }
  if (t < DIM) {
    float u = l1b[t];
    for (int i = 0; i < 2 * DIM; ++i) u = fmaf(qstar[i], l1w[i * DIM + t], u);
    u = fmaxf(u, 0.0f);
    float v = u * l2w[t];
#pragma unroll
    for (int off = 16; off > 0; off >>= 1) v += __shfl_xor(v, off);
    if (t == 0) y[b] = v + l2b[0];
  }
}

extern "C" void kernel_launch(void* const* d_in, const int* in_sizes, int n_in,
                              void* d_out, int out_size, void* d_ws, size_t ws_size,
                              hipStream_t stream) {
  const float* x        = (const float*)d_in[0];
  const float* ea       = (const float*)d_in[1];
  const float* lin0_w   = (const float*)d_in[2];
  const float* lin0_b   = (const float*)d_in[3];
  const float* enn_w1   = (const float*)d_in[4];
  const float* enn_b1   = (const float*)d_in[5];
  const float* enn_w2   = (const float*)d_in[6];
  const float* enn_b2   = (const float*)d_in[7];
  const float* root_w   = (const float*)d_in[8];
  const float* conv_b   = (const float*)d_in[9];
  const float* gru_wih  = (const float*)d_in[10];
  const float* gru_whh  = (const float*)d_in[11];
  const float* gru_bih  = (const float*)d_in[12];
  const float* gru_bhh  = (const float*)d_in[13];
  const float* s2s_wih  = (const float*)d_in[14];
  const float* s2s_whh  = (const float*)d_in[15];
  const float* s2s_bih  = (const float*)d_in[16];
  const float* s2s_bhh  = (const float*)d_in[17];
  const float* lin1_w   = (const float*)d_in[18];
  const float* lin1_b   = (const float*)d_in[19];
  const float* lin2_w   = (const float*)d_in[20];
  const float* lin2_b   = (const float*)d_in[21];
  const int*   ei       = (const int*)d_in[22];
  const int*   batch    = (const int*)d_in[23];
  float* y = (float*)d_out;

  char* p = (char*)d_ws;
  auto alloc = [&](size_t bytes) -> void* {
    void* r = (void*)p;
    p += (bytes + 255) & ~(size_t)255;
    return r;
  };
  float*  out_a   = (float*)alloc(N_NODES * DIM * 4);
  float*  out_b   = (float*)alloc(N_NODES * DIM * 4);
  int*    counts  = (int*)alloc(N_NODES * 4);
  int*    offsets = (int*)alloc((N_NODES + 1) * 4);
  int*    cursor  = (int*)alloc(N_NODES * 4);
  int*    csr_src = (int*)alloc(N_EDGES * 4);
  float2* csr_ea  = (float2*)alloc(N_EDGES * 8);
  float*  deg_inv = (float*)alloc(N_NODES * 4);
  int*    gstart  = (int*)alloc((NGRAPH + 1) * 4);
  float*  Obuf    = (float*)alloc((size_t)N_NODES * DIM * 4);
  float*  partial = (float*)alloc((size_t)2 * N_NODES * DIM * 4);  // 2 MB
  (void)ws_size; (void)n_in; (void)in_sizes; (void)out_size;

  hipMemsetAsync(counts, 0, N_NODES * 4, stream);
  hipMemsetAsync(cursor, 0, N_NODES * 4, stream);

  prep1_kernel<<<1024 + 512, 256, 0, stream>>>(x, lin0_w, lin0_b, out_a,
                                               ei + N_EDGES, counts);
  scan_kernel<<<1, 1024, 0, stream>>>(counts, offsets, deg_inv);
  prep2_kernel<<<512 + 32, 256, 0, stream>>>(ei, ea, offsets, cursor, csr_src,
                                             csr_ea, batch, gstart);

  const int ngroups = (N_NODES + G_NODES - 1) / G_NODES;  // 2731
  const float* cur = out_a;
  float* nxt = out_b;
  for (int layer = 0; layer < 3; ++layer) {
    mp_half_kernel<<<ngroups * 2, 256, 0, stream>>>(
        cur, offsets, csr_src, csr_ea, enn_w1, enn_b1, enn_w2, partial, Obuf);
    epilogue_kernel<<<N_NODES / 8, 256, 0, stream>>>(
        partial, Obuf, cur, enn_b2, deg_inv, root_w, conv_b,
        gru_wih, gru_whh, gru_bih, gru_bhh, nxt);
    const float* tmp = cur; cur = nxt; nxt = (float*)tmp;
  }

  s2s_kernel<<<NGRAPH, 256, 0, stream>>>(cur, gstart, s2s_wih, s2s_whh, s2s_bih,
                                         s2s_bhh, lin1_w, lin1_b, lin2_w, lin2_b, y);
}